// Round 11
// baseline (111.074 us; speedup 1.0000x reference)
//
#include <hip/hip_runtime.h>

#define NJ 24
#define NF 7
#define FS 6
#define THREADS 256
#define CUNITS 12   // float4 per thread per chunk (4 joint-pairs = 192 B)
#define JSTRIDE 128 // floats per joint in LDS weight block

typedef float v4f __attribute__((ext_vector_type(4)));

// parent of each joint; parents[i] < i, so sequential order is topological
__device__ constexpr int kParents[NJ] = {-1, 0, 0, 0, 1, 2, 3, 4, 5, 6, 7, 8,
                                          9, 9, 9, 12, 13, 14, 16, 17, 18, 19, 20, 21};

// LDS weight layout per joint i (base = i*128 floats, all 16B-aligned):
//   [0..55]    W1 rows k=0..6, each padded to 8 (w1[k*8+j], j<7)
//   [56..63]   b1 (7 + pad)
//   [64..119]  W2 rows k=0..6, each padded to 8 (w2[k*8+j], j<6)
//   [120..127] b2 (6 + pad)
// All reads below are uniform-address ds_read_b128 broadcasts (conflict-free,
// compile-time offsets) -- no SMEM, no per-joint s_load serialization.
#define JOINT(i)                                                              \
    {                                                                         \
        const int p_ = kParents[i];                                           \
        float inp_[NF];                                                       \
        inp_[0] = xr[i];                                                      \
        _Pragma("unroll")                                                     \
        for (int j = 0; j < FS; ++j)                                          \
            inp_[1 + j] = (p_ < 0) ? 0.0f : feats[(p_ < 0) ? 0 : p_][j];      \
        float h_[NF];                                                         \
        {                                                                     \
            const v4f* bb = reinterpret_cast<const v4f*>(&sw[(i) * JSTRIDE + 56]); \
            v4f u0 = bb[0], u1 = bb[1];                                       \
            h_[0] = u0.x; h_[1] = u0.y; h_[2] = u0.z; h_[3] = u0.w;           \
            h_[4] = u1.x; h_[5] = u1.y; h_[6] = u1.z;                         \
        }                                                                     \
        _Pragma("unroll")                                                     \
        for (int k = 0; k < NF; ++k) {                                        \
            const float a_ = inp_[k];                                         \
            const v4f* wr = reinterpret_cast<const v4f*>(&sw[(i) * JSTRIDE + k * 8]); \
            v4f w0 = wr[0], w1 = wr[1];                                       \
            h_[0] = fmaf(a_, w0.x, h_[0]); h_[1] = fmaf(a_, w0.y, h_[1]);     \
            h_[2] = fmaf(a_, w0.z, h_[2]); h_[3] = fmaf(a_, w0.w, h_[3]);     \
            h_[4] = fmaf(a_, w1.x, h_[4]); h_[5] = fmaf(a_, w1.y, h_[5]);     \
            h_[6] = fmaf(a_, w1.z, h_[6]);                                    \
        }                                                                     \
        _Pragma("unroll")                                                     \
        for (int j = 0; j < NF; ++j) h_[j] = fmaxf(h_[j], 0.0f);              \
        float f_[FS];                                                         \
        {                                                                     \
            const v4f* bb = reinterpret_cast<const v4f*>(&sw[(i) * JSTRIDE + 120]); \
            v4f u0 = bb[0], u1 = bb[1];                                       \
            f_[0] = u0.x; f_[1] = u0.y; f_[2] = u0.z; f_[3] = u0.w;           \
            f_[4] = u1.x; f_[5] = u1.y;                                       \
        }                                                                     \
        _Pragma("unroll")                                                     \
        for (int k = 0; k < NF; ++k) {                                        \
            const float a_ = h_[k];                                           \
            const v4f* wr = reinterpret_cast<const v4f*>(&sw[(i) * JSTRIDE + 64 + k * 8]); \
            v4f w0 = wr[0], w1 = wr[1];                                       \
            f_[0] = fmaf(a_, w0.x, f_[0]); f_[1] = fmaf(a_, w0.y, f_[1]);     \
            f_[2] = fmaf(a_, w0.z, f_[2]); f_[3] = fmaf(a_, w0.w, f_[3]);     \
            f_[4] = fmaf(a_, w1.x, f_[4]); f_[5] = fmaf(a_, w1.y, f_[5]);     \
        }                                                                     \
        _Pragma("unroll")                                                     \
        for (int j = 0; j < FS; ++j) {                                        \
            f_[j] = fmaxf(f_[j], 0.0f);                                       \
            feats[i][j] = f_[j];                                              \
        }                                                                     \
        if ((i) & 1) { /* stage pair (i-1, i): 3 x v4f into wave-private LDS */ \
            const int pp_ = ((i) >> 1) & 3;                                   \
            v4f* st_ = myStage + pp_ * 3;                                     \
            st_[0] = (v4f){feats[(i) - 1][0], feats[(i) - 1][1],              \
                           feats[(i) - 1][2], feats[(i) - 1][3]};             \
            st_[1] = (v4f){feats[(i) - 1][4], feats[(i) - 1][5],              \
                           f_[0], f_[1]};                                     \
            st_[2] = (v4f){f_[2], f_[3], f_[4], f_[5]};                       \
        }                                                                     \
    }

// Burst flush (R3-proven): 12 ds_read_b128 into the decoupled set fr[], then
// 12 plain stores (full-line coalesced: each = 16 complete 64B lines). Plain
// stores ack at L2 (~200cyc) so fr's next-chunk reuse wait is cheap.
#define FLUSH(C)                                                              \
    {                                                                         \
        _Pragma("unroll")                                                     \
        for (int j = 0; j < CUNITS; ++j) {                                    \
            const int G = j * 64 + lane;                                      \
            const int s = G / CUNITS;                                         \
            const int q = G - s * CUNITS;                                     \
            fr[j] = sm[wid][s * CUNITS + q];                                  \
        }                                                                     \
        _Pragma("unroll")                                                     \
        for (int j = 0; j < CUNITS; ++j) {                                    \
            const int G = j * 64 + lane;                                      \
            const int s = G / CUNITS;                                         \
            const int q = G - s * CUNITS;                                     \
            *reinterpret_cast<v4f*>(                                          \
                reinterpret_cast<char*>(obase) +                              \
                (s * 36 + q) * 16 + (C) * 192) = fr[j];                       \
        }                                                                     \
    }

#define KEEP12(A)                                                             \
    asm volatile("" :: "v"(A[0]), "v"(A[1]), "v"(A[2]), "v"(A[3]),            \
                 "v"(A[4]), "v"(A[5]), "v"(A[6]), "v"(A[7]),                  \
                 "v"(A[8]), "v"(A[9]), "v"(A[10]), "v"(A[11]));

// Requires B % 256 == 0 (bench: B = 524288).
__global__ __launch_bounds__(THREADS, 2) void se1d_kernel(
    const float* __restrict__ x,
    const float* __restrict__ W1,
    const float* __restrict__ b1,
    const float* __restrict__ W2,
    const float* __restrict__ b2,
    float* __restrict__ out, int B)
{
    __shared__ float sw[NJ * JSTRIDE];          // 12288 B weights
    __shared__ v4f sm[THREADS / 64][64 * CUNITS];  // 49152 B staging (no pad)

    const int t    = threadIdx.x;
    const int lane = t & 63;
    const int wid  = __builtin_amdgcn_readfirstlane(threadIdx.x >> 6);
    const int b    = blockIdx.x * THREADS + t;         // this thread's sample
    const int wb   = blockIdx.x * THREADS + wid * 64;  // wave base (uniform)

    // Stage all weights into padded-row LDS layout (once per block, 12 iters).
    for (int idx = t; idx < NJ * JSTRIDE; idx += THREADS) {
        const int jnt = idx >> 7, r = idx & 127;
        float v = 0.0f;
        if (r < 56) {
            const int k = r >> 3, j = r & 7;
            if (j < NF) v = W1[jnt * NF * NF + k * NF + j];
        } else if (r < 64) {
            const int j = r - 56;
            if (j < NF) v = b1[jnt * NF + j];
        } else if (r < 120) {
            const int k = (r - 64) >> 3, j = (r - 64) & 7;
            if (j < FS) v = W2[jnt * NF * FS + k * FS + j];
        } else {
            const int j = r - 120;
            if (j < FS) v = b2[jnt * FS + j];
        }
        sw[idx] = v;
    }

    v4f* const myStage = &sm[wid][lane * CUNITS];
    v4f* const obase = reinterpret_cast<v4f*>(out) + (size_t)wb * 36;

    // All x up-front (96 B contiguous, 16B-aligned).
    float xr[NJ];
    {
        const v4f* xv = reinterpret_cast<const v4f*>(x + (size_t)b * NJ);
        #pragma unroll
        for (int c = 0; c < NJ / 4; ++c) {
            v4f v = xv[c];
            xr[c * 4 + 0] = v.x; xr[c * 4 + 1] = v.y;
            xr[c * 4 + 2] = v.z; xr[c * 4 + 3] = v.w;
        }
    }

    __syncthreads();  // weights staged; rest of kernel is barrier-free

    float feats[NJ][FS];  // fully unrolled -> registers, ~3 joints live
    v4f fr[CUNITS];       // decoupled store-data set (pinned)

    JOINT(0) JOINT(1) JOINT(2) JOINT(3) JOINT(4) JOINT(5) JOINT(6) JOINT(7)
    FLUSH(0);
    JOINT(8) JOINT(9) JOINT(10) JOINT(11)
    JOINT(12) JOINT(13) JOINT(14) JOINT(15)
    FLUSH(1);
    JOINT(16) JOINT(17) JOINT(18) JOINT(19)
    JOINT(20) JOINT(21) JOINT(22) JOINT(23)
    FLUSH(2);

    KEEP12(fr);
    (void)B;
}

extern "C" void kernel_launch(void* const* d_in, const int* in_sizes, int n_in,
                              void* d_out, int out_size, void* d_ws, size_t ws_size,
                              hipStream_t stream) {
    const float* x  = (const float*)d_in[0];
    const float* W1 = (const float*)d_in[1];
    const float* b1 = (const float*)d_in[2];
    const float* W2 = (const float*)d_in[3];
    const float* b2 = (const float*)d_in[4];
    float* out = (float*)d_out;
    const int B = in_sizes[0] / NJ;   // 524288, multiple of 256
    const int grid = B / THREADS;
    hipLaunchKernelGGL(se1d_kernel, dim3(grid), dim3(THREADS), 0, stream,
                       x, W1, b1, W2, b2, out, B);
}